// Round 13
// baseline (277.530 us; speedup 1.0000x reference)
//
#include <hip/hip_runtime.h>

// GNN: N=50000 nodes, E=800000 edges, IN=128, HID=64, OUT=128, EH=32, 3 etypes, 2 ntypes.
//
// Strategy:
//   feat @ eW[e] = nf[src] @ eW[e][:IN] + nf[dst] @ eW[e][IN:]
//   => per-node projections P[n][192] (fp16), per-edge gather over bucket-CSR-by-dst,
//      node MLP type-partitioned. All GEMMs via MFMA bf16 3-term split (fp32 accum).
//
// R1-R12: scans, partition, deg8 CSR, float4/8-slot agg, mlp2 MFMA (331->296).
// R13 FAILED fp16 4-lane. R14: agg beyond-L2-throughput bound. R15: fp16 8-lane (286).
// R16 FAILED segmented fusion. R17: stride-interleaved proj under rank's fabric shadow
//      (278.8). R18 NEUTRAL/NEG. R19: shadow spare capacity. R20: prep+partition hidden
//      (278.3). R21: one-pass 64-slot bucket CSR (2E fabric ops, no scan) -> 255.5.
// R22: aggregate = TWO dst nodes per wave, 4 gathers in flight before accumulation
//      (was 2). A/B test: outstanding-limited (Little's law ~9tx/ns at 2/wave) vs
//      fabric floor (~19tx/ns). If outstanding-limited, agg 40->~27 each.

typedef __attribute__((ext_vector_type(8))) short bf16x8_t;   // 8 bf16 in 4 VGPRs
typedef __attribute__((ext_vector_type(4))) float f32x4_t;
typedef _Float16 f16;
typedef __attribute__((ext_vector_type(4))) _Float16 f16x4_t; // 8B
typedef __attribute__((ext_vector_type(8))) _Float16 f16x8_t; // 16B

__device__ __forceinline__ void cvt_split(float x, unsigned short& h, unsigned short& l) {
  unsigned u = __float_as_uint(x);
  unsigned rh = u + 0x7FFFu + ((u >> 16) & 1u);
  h = (unsigned short)(rh >> 16);
  float xh = __uint_as_float((unsigned)h << 16);
  float xl = x - xh;
  unsigned v = __float_as_uint(xl);
  unsigned rl = v + 0x7FFFu + ((v >> 16) & 1u);
  l = (unsigned short)(rl >> 16);
}

// ---------------- W fragment prep (device body) ----------------

template <int IN, int OUT>
__device__ __forceinline__ void prep_dev(int id,
                                         const float* __restrict__ eW,
                                         float* __restrict__ wfh,
                                         float* __restrict__ wfl,
                                         const float* __restrict__ nW,
                                         float* __restrict__ wnh,
                                         float* __restrict__ wnl) {
  constexpr int KC = IN / 32;
  constexpr int CT = OUT / 16;
  if (id < 12 * KC * 64) {
    int lane = id & 63;
    int fk = id >> 6;
    int kc = fk % KC, ct = fk / KC;
    int n = ct * 16 + (lane & 15);
    int kb = kc * 32 + ((lane >> 4) & 3) * 8;
    int half = (n >= 96) ? 1 : 0;
    int jj = n - 96 * half;
    int e = jj >> 5, o = jj & 31;
    const float* wp = eW + ((size_t)((e * 2 + half) * IN) + kb) * 32 + o;
    bf16x8_t hv, lv;
#pragma unroll
    for (int j = 0; j < 8; ++j) {
      unsigned short h, l;
      cvt_split(wp[(size_t)j * 32], h, l);
      hv[j] = (short)h;
      lv[j] = (short)l;
    }
    *(bf16x8_t*)(wfh + (size_t)id * 4) = hv;
    *(bf16x8_t*)(wfl + (size_t)id * 4) = lv;
    return;
  }
  int id2 = id - 12 * KC * 64;
  if (id2 >= 2 * CT * 3 * 64) return;
  // nW frag: B[lane][j] = nW[t][kc*32 + ((lane>>4)&3)*8 + j][ct*16 + (lane&15)]
  int lane = id2 & 63;
  int fk = id2 >> 6;
  int kc = fk % 3;
  int ct = (fk / 3) % CT;
  int t = fk / (3 * CT);
  const float* wp = nW + ((size_t)t * 96 + kc * 32 + ((lane >> 4) & 3) * 8) * OUT +
                    ct * 16 + (lane & 15);
  bf16x8_t hv, lv;
#pragma unroll
  for (int j = 0; j < 8; ++j) {
    unsigned short h, l;
    cvt_split(wp[(size_t)j * OUT], h, l);
    hv[j] = (short)h;
    lv[j] = (short)l;
  }
  *(bf16x8_t*)(wnh + (size_t)id2 * 4) = hv;
  *(bf16x8_t*)(wnl + (size_t)id2 * 4) = lv;
}

// ---------------- node projection GEMM via MFMA (device body; fp16 P output) --------

template <int IN>
__device__ __forceinline__ void proj_dev(int bid,
                                         const float* __restrict__ X,
                                         const float* __restrict__ wfh,
                                         const float* __restrict__ wfl,
                                         f16* __restrict__ P, int n) {
  constexpr int KC = IN / 32;
  __shared__ short Ah[4 * KC * 64 * 8];
  __shared__ short Al[4 * KC * 64 * 8];
  const int tx = threadIdx.x;
  const int base = bid * 64;

  for (int q = tx; q < 4 * KC * 64; q += 256) {
    int lane = q & 63;
    int fk = q >> 6;
    int kc = fk % KC, nt = fk / KC;
    int node = base + nt * 16 + (lane & 15);
    int kb = kc * 32 + ((lane >> 4) & 3) * 8;
    float xs[8];
    if (node < n) {
      float4 a = *(const float4*)(X + (size_t)node * IN + kb);
      float4 b = *(const float4*)(X + (size_t)node * IN + kb + 4);
      xs[0] = a.x; xs[1] = a.y; xs[2] = a.z; xs[3] = a.w;
      xs[4] = b.x; xs[5] = b.y; xs[6] = b.z; xs[7] = b.w;
    } else {
#pragma unroll
      for (int j = 0; j < 8; ++j) xs[j] = 0.f;
    }
    bf16x8_t hv, lv;
#pragma unroll
    for (int j = 0; j < 8; ++j) {
      unsigned short h, l;
      cvt_split(xs[j], h, l);
      hv[j] = (short)h;
      lv[j] = (short)l;
    }
    *(bf16x8_t*)(Ah + (size_t)q * 8) = hv;
    *(bf16x8_t*)(Al + (size_t)q * 8) = lv;
  }
  __syncthreads();

  const int wave = tx >> 6;
  const int lane = tx & 63;

  f32x4_t acc[4][3];
#pragma unroll
  for (int nt = 0; nt < 4; ++nt)
#pragma unroll
    for (int c = 0; c < 3; ++c) acc[nt][c] = (f32x4_t){0.f, 0.f, 0.f, 0.f};

  for (int kc = 0; kc < KC; ++kc) {
    bf16x8_t Bh[3], Bl[3];
#pragma unroll
    for (int c = 0; c < 3; ++c) {
      int ct = wave * 3 + c;
      size_t idx = ((size_t)(ct * KC + kc) * 64 + lane) * 4;
      Bh[c] = *(const bf16x8_t*)(wfh + idx);
      Bl[c] = *(const bf16x8_t*)(wfl + idx);
    }
#pragma unroll
    for (int nt = 0; nt < 4; ++nt) {
      size_t idx = ((size_t)(nt * KC + kc) * 64 + lane) * 8;
      bf16x8_t ah = *(const bf16x8_t*)(Ah + idx);
      bf16x8_t al = *(const bf16x8_t*)(Al + idx);
#pragma unroll
      for (int c = 0; c < 3; ++c) {
        acc[nt][c] = __builtin_amdgcn_mfma_f32_16x16x32_bf16(ah, Bh[c], acc[nt][c], 0, 0, 0);
        acc[nt][c] = __builtin_amdgcn_mfma_f32_16x16x32_bf16(ah, Bl[c], acc[nt][c], 0, 0, 0);
        acc[nt][c] = __builtin_amdgcn_mfma_f32_16x16x32_bf16(al, Bh[c], acc[nt][c], 0, 0, 0);
      }
    }
  }

  const int row0 = ((lane >> 4) & 3) * 4;
  const int col = lane & 15;
#pragma unroll
  for (int nt = 0; nt < 4; ++nt) {
#pragma unroll
    for (int c = 0; c < 3; ++c) {
      int jcol = (wave * 3 + c) * 16 + col;
#pragma unroll
      for (int r = 0; r < 4; ++r) {
        int node = base + nt * 16 + row0 + r;
        if (node < n) P[(size_t)node * 192 + jcol] = (f16)acc[nt][c][r];
      }
    }
  }
}

template <int IN>
__global__ __launch_bounds__(256) void proj_mfma(const float* __restrict__ X,
                                                 const float* __restrict__ wfh,
                                                 const float* __restrict__ wfl,
                                                 f16* __restrict__ P, int n) {
  proj_dev<IN>(blockIdx.x, X, wfh, wfl, P, n);
}

// ---------------- one-pass bucket scatter (device body) ----------------
// bucket[d*64 + atomicAdd(cnt[d])] = src*384 + et*65. Capacity 64 (P(deg>=64)~4e-18).

__device__ __forceinline__ void scatter_dev(int i,
                                            const int* __restrict__ src,
                                            const int* __restrict__ dst,
                                            const int* __restrict__ etype,
                                            int* __restrict__ cnt,
                                            int* __restrict__ bucket) {
  int d = dst[i];
  int pos = atomicAdd(&cnt[d], 1);
  if (pos < 64) bucket[(size_t)d * 64 + pos] = src[i] * 384 + etype[i] * 65;
}

// ---------------- D1: prep(36) + partition + scatter edges [0, e1) ----------------

__global__ __launch_bounds__(256) void fusedA(const float* __restrict__ eW0,
                                              float* __restrict__ wf0h, float* __restrict__ wf0l,
                                              const float* __restrict__ nW1,
                                              float* __restrict__ wn1h, float* __restrict__ wn1l,
                                              const float* __restrict__ eW1,
                                              float* __restrict__ wf1h, float* __restrict__ wf1l,
                                              const float* __restrict__ nW0,
                                              float* __restrict__ wn0h, float* __restrict__ wn0l,
                                              const int* __restrict__ src,
                                              const int* __restrict__ dst,
                                              const int* __restrict__ etype,
                                              int* __restrict__ cnt,
                                              int* __restrict__ bucket, int e1,
                                              const int* __restrict__ ntype,
                                              int* __restrict__ idxbuf,
                                              int* __restrict__ tcnt, int n, int ncap,
                                              int pargrid) {
  int bid = blockIdx.x;
  if (bid < 24) {
    prep_dev<128, 128>(bid * 256 + threadIdx.x, eW0, wf0h, wf0l, nW1, wn1h, wn1l);
    return;
  }
  if (bid < 36) {
    prep_dev<64, 64>((bid - 24) * 256 + threadIdx.x, eW1, wf1h, wf1l, nW0, wn0h, wn0l);
    return;
  }
  bid -= 36;
  if (bid < pargrid) {
    int i = bid * 256 + threadIdx.x;
    int lane = threadIdx.x & 63;
    int t = (i < n) ? ntype[i] : -1;
    unsigned long long m0 = __ballot(t == 0);
    unsigned long long m1 = __ballot(t == 1);
    int b0 = 0, b1 = 0;
    if (lane == 0) {
      b0 = atomicAdd(&tcnt[0], (int)__popcll(m0));
      b1 = atomicAdd(&tcnt[1], (int)__popcll(m1));
    }
    b0 = __shfl(b0, 0);
    b1 = __shfl(b1, 0);
    unsigned long long below = (1ull << lane) - 1ull;
    if (t == 0) idxbuf[b0 + (int)__popcll(m0 & below)] = i;
    else if (t == 1) idxbuf[ncap + b1 + (int)__popcll(m1 & below)] = i;
    return;
  }
  bid -= pargrid;
  int i = bid * 256 + threadIdx.x;
  if (i < e1) scatter_dev(i, src, dst, etype, cnt, bucket);
}

// ---------------- D2: scatter edges [e1, E) + ALL proj128, stride interleave --------

__global__ __launch_bounds__(256) void fusedB(const float* __restrict__ X,
                                              const float* __restrict__ wfh,
                                              const float* __restrict__ wfl,
                                              f16* __restrict__ P, int n,
                                              int npb, int stride,
                                              const int* __restrict__ src,
                                              const int* __restrict__ dst,
                                              const int* __restrict__ etype,
                                              int* __restrict__ cnt,
                                              int* __restrict__ bucket,
                                              int e1, int E) {
  int bid = blockIdx.x;
  int pb = bid / stride;
  if ((bid % stride) == 0 && pb < npb) {
    proj_dev<128>(pb, X, wfh, wfl, P, n);
    return;
  }
  int nproj_before = (bid % stride == 0) ? pb : (pb + 1);
  if (nproj_before > npb) nproj_before = npb;
  int j = bid - nproj_before;
  int i = e1 + j * 256 + threadIdx.x;
  if (i < E) scatter_dev(i, src, dst, etype, cnt, bucket);
}

// ---------------- edge aggregation: TWO dst nodes per wave, 4 gathers in flight -----

#define ACC_EDGEH2(pk, v, A0, A1, A2, C0, C1, PD0, PD1, PD2)          \
  {                                                                   \
    int et_ = (pk) & 3;                                               \
    bool e0_ = (et_ == 0), e1_ = (et_ == 1), e2_ = (et_ == 2);        \
    _Pragma("unroll")                                                 \
    for (int j = 0; j < 4; ++j) {                                     \
      float pb_ = e0_ ? PD0[j] : (e1_ ? PD1[j] : PD2[j]);             \
      float m_ = fmaxf((float)(v)[j] + pb_, 0.f);                     \
      A0[j] += e0_ ? m_ : 0.f;                                        \
      A1[j] += e1_ ? m_ : 0.f;                                        \
      A2[j] += e2_ ? m_ : 0.f;                                        \
    }                                                                 \
    C0 += e0_; C1 += e1_;                                             \
  }

__global__ __launch_bounds__(256) void aggregate_kernel(const f16* __restrict__ P,
                                                        const int* __restrict__ cnt,
                                                        const int* __restrict__ bucket,
                                                        const float* __restrict__ eb,
                                                        f16* __restrict__ h, int n) {
  int wp = (blockIdx.x * 256 + threadIdx.x) >> 6;  // wave id = node pair
  int na = wp * 2, nb = na + 1;
  if (na >= n) return;
  bool hasb = (nb < n);
  int lane = threadIdx.x & 63;
  int co = (lane & 7) * 4;   // 4 halves per lane within the 32-col chunk
  int cb = co * 2;           // byte offset within the 64B chunk
  int slot = lane >> 3;      // 0..7 : 8 edges per node per load round

  float4 e0v = *(const float4*)(eb + co);
  float4 e1v = *(const float4*)(eb + 32 + co);
  float4 e2v = *(const float4*)(eb + 64 + co);

  const f16* PdA = P + (size_t)na * 192 + 96;
  const f16* PdB = P + (size_t)(hasb ? nb : na) * 192 + 96;
  float pdA0[4], pdA1[4], pdA2[4], pdB0[4], pdB1[4], pdB2[4];
  {
    f16x4_t a0_ = *(const f16x4_t*)(PdA + co);
    f16x4_t a1_ = *(const f16x4_t*)(PdA + 32 + co);
    f16x4_t a2_ = *(const f16x4_t*)(PdA + 64 + co);
    f16x4_t b0_ = *(const f16x4_t*)(PdB + co);
    f16x4_t b1_ = *(const f16x4_t*)(PdB + 32 + co);
    f16x4_t b2_ = *(const f16x4_t*)(PdB + 64 + co);
    pdA0[0] = (float)a0_[0] + e0v.x; pdA0[1] = (float)a0_[1] + e0v.y;
    pdA0[2] = (float)a0_[2] + e0v.z; pdA0[3] = (float)a0_[3] + e0v.w;
    pdA1[0] = (float)a1_[0] + e1v.x; pdA1[1] = (float)a1_[1] + e1v.y;
    pdA1[2] = (float)a1_[2] + e1v.z; pdA1[3] = (float)a1_[3] + e1v.w;
    pdA2[0] = (float)a2_[0] + e2v.x; pdA2[1] = (float)a2_[1] + e2v.y;
    pdA2[2] = (float)a2_[2] + e2v.z; pdA2[3] = (float)a2_[3] + e2v.w;
    pdB0[0] = (float)b0_[0] + e0v.x; pdB0[1] = (float)b0_[1] + e0v.y;
    pdB0[2] = (float)b0_[2] + e0v.z; pdB0[3] = (float)b0_[3] + e0v.w;
    pdB1[0] = (float)b1_[0] + e1v.x; pdB1[1] = (float)b1_[1] + e1v.y;
    pdB1[2] = (float)b1_[2] + e1v.z; pdB1[3] = (float)b1_[3] + e1v.w;
    pdB2[0] = (float)b2_[0] + e2v.x; pdB2[1] = (float)b2_[1] + e2v.y;
    pdB2[2] = (float)b2_[2] + e2v.z; pdB2[3] = (float)b2_[3] + e2v.w;
  }

  int cnA = cnt[na]; cnA = (cnA > 64) ? 64 : cnA;
  int cnB = hasb ? cnt[nb] : 0; cnB = (cnB > 64) ? 64 : cnB;
  int sa = na * 64, sb = nb * 64;
  int ea = sa + cnA, ebb = sb + cnB;

  const char* Pb = (const char*)P;
  float aA0[4], aA1[4], aA2[4], aB0[4], aB1[4], aB2[4];
#pragma unroll
  for (int j = 0; j < 4; ++j) {
    aA0[j] = 0.f; aA1[j] = 0.f; aA2[j] = 0.f;
    aB0[j] = 0.f; aB1[j] = 0.f; aB2[j] = 0.f;
  }
  int c0A = 0, c1A = 0, c0B = 0, c1B = 0;

  int ia = sa + slot, ib = sb + slot;
  while (ia < ea || ib < ebb) {
    // issue ALL FOUR payload reads, then ALL FOUR gathers, before accumulating
    int pa0 = (ia < ea) ? bucket[ia] : 3;
    int pa1 = (ia + 8 < ea) ? bucket[ia + 8] : 3;
    int pb0 = (ib < ebb) ? bucket[ib] : 3;
    int pb1 = (ib + 8 < ebb) ? bucket[ib + 8] : 3;
    f16x4_t va0 = *(const f16x4_t*)(Pb + (size_t)(pa0 & ~3) + cb);
    f16x4_t va1 = *(const f16x4_t*)(Pb + (size_t)(pa1 & ~3) + cb);
    f16x4_t vb0 = *(const f16x4_t*)(Pb + (size_t)(pb0 & ~3) + cb);
    f16x4_t vb1 = *(const f16x4_t*)(Pb + (size_t)(pb1 & ~3) + cb);
    ACC_EDGEH2(pa0, va0, aA0, aA1, aA2, c0A, c1A, pdA0, pdA1, pdA2)
    ACC_EDGEH2(pa1, va1, aA0, aA1, aA2, c0A, c1A, pdA0, pdA1, pdA2)
    ACC_EDGEH2(pb0, vb0, aB0, aB1, aB2, c0B, c1B, pdB0, pdB1, pdB2)
    ACC_EDGEH2(pb1, vb1, aB0, aB1, aB2, c0B, c1B, pdB0, pdB1, pdB2)
    ia += 16; ib += 16;
  }

#pragma unroll
  for (int off = 8; off < 64; off <<= 1) {
#pragma unroll
    for (int j = 0; j < 4; ++j) {
      aA0[j] += __shfl_xor(aA0[j], off);
      aA1[j] += __shfl_xor(aA1[j], off);
      aA2[j] += __shfl_xor(aA2[j], off);
      aB0[j] += __shfl_xor(aB0[j], off);
      aB1[j] += __shfl_xor(aB1[j], off);
      aB2[j] += __shfl_xor(aB2[j], off);
    }
    c0A += __shfl_xor(c0A, off);
    c1A += __shfl_xor(c1A, off);
    c0B += __shfl_xor(c0B, off);
    c1B += __shfl_xor(c1B, off);
  }

  if (slot == 0) {
    float d0 = fmaxf((float)c0A, 1.f);
    float d1 = fmaxf((float)c1A, 1.f);
    float d2 = fmaxf((float)(cnA - c0A - c1A), 1.f);
    f16* hn = h + (size_t)na * 96;
    f16x4_t o0, o1, o2;
#pragma unroll
    for (int j = 0; j < 4; ++j) {
      o0[j] = (f16)(aA0[j] / d0);
      o1[j] = (f16)(aA1[j] / d1);
      o2[j] = (f16)(aA2[j] / d2);
    }
    *(f16x4_t*)(hn + co)      = o0;
    *(f16x4_t*)(hn + 32 + co) = o1;
    *(f16x4_t*)(hn + 64 + co) = o2;
  } else if (slot == 1 && hasb) {
    float d0 = fmaxf((float)c0B, 1.f);
    float d1 = fmaxf((float)c1B, 1.f);
    float d2 = fmaxf((float)(cnB - c0B - c1B), 1.f);
    f16* hn = h + (size_t)nb * 96;
    f16x4_t o0, o1, o2;
#pragma unroll
    for (int j = 0; j < 4; ++j) {
      o0[j] = (f16)(aB0[j] / d0);
      o1[j] = (f16)(aB1[j] / d1);
      o2[j] = (f16)(aB2[j] / d2);
    }
    *(f16x4_t*)(hn + co)      = o0;
    *(f16x4_t*)(hn + 32 + co) = o1;
    *(f16x4_t*)(hn + 64 + co) = o2;
  }
}

// ---------------- node MLP via MFMA (type-partitioned gathered GEMM, fp16 H) --------

template <int OUT>
__global__ __launch_bounds__(256) void mlp2_mfma(const f16* __restrict__ H,
                                                 const float* __restrict__ wnh,
                                                 const float* __restrict__ wnl,
                                                 const float* __restrict__ nb,
                                                 const int* __restrict__ idxbuf,
                                                 const int* __restrict__ tcnt,
                                                 float* __restrict__ out, int ncap) {
  constexpr int CT = OUT / 16;
  constexpr int CW = CT / 4;  // col-tiles per wave
  __shared__ short Ah[12 * 64 * 8];  // [mt*3+kc][lane][8]
  __shared__ short Al[12 * 64 * 8];

  int c0 = tcnt[0];
  int nb0 = (c0 + 63) >> 6;
  int t, base, cnt;
  if ((int)blockIdx.x < nb0) {
    t = 0; base = blockIdx.x << 6; cnt = c0;
  } else {
    t = 1; base = ((int)blockIdx.x - nb0) << 6; cnt = tcnt[1];
    if (base >= cnt) return;
  }
  const int* il = idxbuf + (size_t)t * ncap;
  const float* bias = nb + t * OUT;

  const int tx = threadIdx.x;
  for (int q = tx; q < 12 * 64; q += 256) {
    int lane = q & 63;
    int fk = q >> 6;
    int kc = fk % 3, mt = fk / 3;
    int slot = base + mt * 16 + (lane & 15);
    int kb = kc * 32 + ((lane >> 4) & 3) * 8;
    float xs[8];
    if (slot < cnt) {
      int row = il[slot];
      f16x8_t a = *(const f16x8_t*)(H + (size_t)row * 96 + kb);
#pragma unroll
      for (int j = 0; j < 8; ++j) xs[j] = (float)a[j];
    } else {
#pragma unroll
      for (int j = 0; j < 8; ++j) xs[j] = 0.f;
    }
    bf16x8_t hv, lv;
#pragma unroll
    for (int j = 0; j < 8; ++j) {
      unsigned short h, l;
      cvt_split(xs[j], h, l);
      hv[j] = (short)h;
      lv[j] = (short)l;
    }
    *(bf16x8_t*)(Ah + (size_t)q * 8) = hv;
    *(bf16x8_t*)(Al + (size_t)q * 8) = lv;
  }
  __syncthreads();

  const int wave = tx >> 6;
  const int lane = tx & 63;

  f32x4_t acc[4][CW];
#pragma unroll
  for (int mt = 0; mt < 4; ++mt)
#pragma unroll
    for (int c = 0; c < CW; ++c) acc[mt][c] = (f32x4_t){0.f, 0.f, 0.f, 0.f};

  for (int kc = 0; kc < 3; ++kc) {
    bf16x8_t Bh[CW], Bl[CW];
#pragma unroll
    for (int c = 0; c < CW; ++c) {
      int ct = wave * CW + c;
      size_t idx = ((size_t)((t * CT + ct) * 3 + kc) * 64 + lane) * 4;
      Bh[c] = *(const bf16x8_t*)(wnh + idx);
      Bl[c] = *(const bf16x8_t*)(wnl + idx);
    }
#pragma unroll
    for (int mt = 0; mt < 4; ++mt) {
      size_t idx = ((size_t)((mt * 3 + kc) * 64) + lane) * 8;
      bf16x8_t ah = *(const bf16x8_t*)(Ah + idx);
      bf16x8_t al = *(const bf16x8_t*)(Al + idx);
#pragma unroll
      for (int c = 0; c < CW; ++c) {
        acc[mt][c] = __builtin_amdgcn_mfma_f32_16x16x32_bf16(ah, Bh[c], acc[mt][c], 0, 0, 0);
        acc[mt][c] = __builtin_amdgcn_mfma_f32_16x16x32_bf16(ah, Bl[c], acc[mt][c], 0, 0, 0);
        acc[mt][c] = __builtin_amdgcn_mfma_f32_16x16x32_bf16(al, Bh[c], acc[mt][c], 0, 0, 0);
      }
    }
  }

  const int row0 = ((lane >> 4) & 3) * 4;
  const int col = lane & 15;
#pragma unroll
  for (int mt = 0; mt < 4; ++mt) {
#pragma unroll
    for (int c = 0; c < CW; ++c) {
      int jcol = (wave * CW + c) * 16 + col;
      float bj = bias[jcol];
#pragma unroll
      for (int r = 0; r < 4; ++r) {
        int slot = base + mt * 16 + row0 + r;
        if (slot < cnt) {
          int row = il[slot];
          out[(size_t)row * OUT + jcol] = fmaxf(acc[mt][c][r] + bj, 0.f);
        }
      }
    }
  }
}

// ---------------- launch ----------------

extern "C" void kernel_launch(void* const* d_in, const int* in_sizes, int n_in,
                              void* d_out, int out_size, void* d_ws, size_t ws_size,
                              hipStream_t stream) {
  const float* nf    = (const float*)d_in[0];
  const int*   eidx  = (const int*)d_in[1];
  const int*   etype = (const int*)d_in[2];
  const int*   ntype = (const int*)d_in[3];
  const float* eW0   = (const float*)d_in[4];
  const float* eb0   = (const float*)d_in[5];
  const float* nW0   = (const float*)d_in[6];
  const float* nb0   = (const float*)d_in[7];
  const float* eW1   = (const float*)d_in[8];
  const float* eb1   = (const float*)d_in[9];
  const float* nW1   = (const float*)d_in[10];
  const float* nb1   = (const float*)d_in[11];
  const int N = in_sizes[3];
  const int E = in_sizes[2];
  const int* srcv = eidx;
  const int* dstv = eidx + E;

  // workspace layout. fp16 P uses the FIRST half of its fp32-sized region; the free
  // upper half [N*96, N*192) floats hosts the bucket array (N*64 ints <= N*96 floats).
  float* ws  = (float*)d_ws;
  f16*   P   = (f16*)ws;                               // N*192 f16 = N*96 floats
  int* bucket = (int*)(ws + (size_t)N * 96);           // N*64 ints (in P region's free half)
  f16*   h96 = (f16*)(ws + (size_t)N * 192);           // region N*96 floats
  float* h64 = ws + (size_t)N * 192 + (size_t)N * 96;  // region N*64 floats
  int* cnt_     = (int*)(h64 + (size_t)N * 64);   // N
  int* tcnt     = cnt_ + ((N + 4) & ~3);          // 2 (+pad)
  int* idxbuf   = tcnt + 4;                       // 2*N
  float* wf0h   = (float*)(idxbuf + 2 * N);       // 12288
  float* wf0l   = wf0h + 12288;                   // 12288
  float* wf1h   = wf0l + 12288;                   // 6144
  float* wf1l   = wf1h + 6144;                    // 6144
  float* wn0h   = wf1l + 6144;                    // 6144
  float* wn0l   = wn0h + 6144;                    // 6144
  float* wn1h   = wn0l + 6144;                    // 12288
  float* wn1l   = wn1h + 12288;                   // 12288

  const int pargrid = (N + 255) / 256;
  const int pgrid = (N + 63) / 64;
  const int e1 = (E / 2 + 255) & ~255;            // scatter split, 256-aligned
  const int sg1 = (e1 + 255) / 256;               // D1 scatter blocks
  const int sg2 = (E - e1 + 255) / 256;           // D2 scatter blocks

  // 0) zero cnt + tcnt (one contiguous fill).
  hipMemsetAsync(cnt_, 0, (size_t)(((N + 4) & ~3) + 4) * sizeof(int), stream);
  // 1) D1: prep(36) + partition + scatter[0, e1).
  fusedA<<<36 + pargrid + sg1, 256, 0, stream>>>(
      eW0, wf0h, wf0l, nW1, wn1h, wn1l,
      eW1, wf1h, wf1l, nW0, wn0h, wn0l,
      srcv, dstv, etype, cnt_, bucket, e1,
      ntype, idxbuf, tcnt, N, N, pargrid);
  // 2) D2: scatter[e1, E) + ALL proj128 (stride interleave).
  {
    int G = pgrid + sg2;
    int stride = G / pgrid;
    if (stride < 1) stride = 1;
    fusedB<<<G, 256, 0, stream>>>(nf, wf0h, wf0l, P, N, pgrid, stride,
                                  srcv, dstv, etype, cnt_, bucket, e1, E);
  }

  const int npairs = (N + 1) / 2;
  int agrid = (npairs + 3) / 4;   // 4 waves/block, 2 nodes/wave
  int mgrid = (N + 63) / 64 + 2;

  // layer 0: aggregate -> mlp2<64> (fp32 h64) ; layer 1: proj64 -> aggregate -> mlp2<128>.
  aggregate_kernel<<<agrid, 256, 0, stream>>>(P, cnt_, bucket, eb0, h96, N);
  mlp2_mfma<64><<<mgrid, 256, 0, stream>>>(h96, wn0h, wn0l, nb0, idxbuf, tcnt, h64, N);
  proj_mfma<64><<<pgrid, 256, 0, stream>>>(h64, wf1h, wf1l, P, N);
  aggregate_kernel<<<agrid, 256, 0, stream>>>(P, cnt_, bucket, eb1, h96, N);
  mlp2_mfma<128><<<mgrid, 256, 0, stream>>>(h96, wn1h, wn1l, nb1, idxbuf, tcnt, (float*)d_out, N);
}

// Round 14
// 258.070 us; speedup vs baseline: 1.0754x; 1.0754x over previous
//
#include <hip/hip_runtime.h>

// GNN: N=50000 nodes, E=800000 edges, IN=128, HID=64, OUT=128, EH=32, 3 etypes, 2 ntypes.
//
// Strategy:
//   feat @ eW[e] = nf[src] @ eW[e][:IN] + nf[dst] @ eW[e][IN:]
//   => per-node projections P[n][192] (fp16), per-edge gather over bucket-CSR-by-dst,
//      node MLP type-partitioned. All GEMMs via MFMA bf16 3-term split (fp32 accum).
//
// R1-R12: scans, partition, deg8 CSR, float4/8-slot agg, mlp2 MFMA (331->296).
// R13 FAILED fp16 4-lane. R14: agg beyond-L2-throughput bound. R15: fp16 8-lane (286).
// R16 FAILED segmented fusion. R17: stride-interleaved proj under rank's fabric shadow
//      (278.8). R18 NEUTRAL/NEG. R19: shadow spare capacity. R20: prep+partition hidden
//      (278.3). R21: one-pass 64-slot bucket CSR (2E fabric ops, no scan) -> 255.5.
// R22 FAILED (277.5): 2-node/wave aggregate went VALU-bound (74% VALUBusy) — agg is
//      at VALU/fabric balance, NOT outstanding-limited; doubled reduction tree +
//      sentinel waste cost more than the concurrency bought. REVERTED.
// R23: exact R21 restore (best = 255.5). Aggregate select-accumulate VALU is
//      inherent (relu binds pdb[et] per-edge); per-type sub-buckets risk overflow;
//      fp16 accum risks absmax. Structural floor candidates all measured.

typedef __attribute__((ext_vector_type(8))) short bf16x8_t;   // 8 bf16 in 4 VGPRs
typedef __attribute__((ext_vector_type(4))) float f32x4_t;
typedef _Float16 f16;
typedef __attribute__((ext_vector_type(4))) _Float16 f16x4_t; // 8B
typedef __attribute__((ext_vector_type(8))) _Float16 f16x8_t; // 16B

__device__ __forceinline__ void cvt_split(float x, unsigned short& h, unsigned short& l) {
  unsigned u = __float_as_uint(x);
  unsigned rh = u + 0x7FFFu + ((u >> 16) & 1u);
  h = (unsigned short)(rh >> 16);
  float xh = __uint_as_float((unsigned)h << 16);
  float xl = x - xh;
  unsigned v = __float_as_uint(xl);
  unsigned rl = v + 0x7FFFu + ((v >> 16) & 1u);
  l = (unsigned short)(rl >> 16);
}

// ---------------- W fragment prep (device body) ----------------

template <int IN, int OUT>
__device__ __forceinline__ void prep_dev(int id,
                                         const float* __restrict__ eW,
                                         float* __restrict__ wfh,
                                         float* __restrict__ wfl,
                                         const float* __restrict__ nW,
                                         float* __restrict__ wnh,
                                         float* __restrict__ wnl) {
  constexpr int KC = IN / 32;
  constexpr int CT = OUT / 16;
  if (id < 12 * KC * 64) {
    int lane = id & 63;
    int fk = id >> 6;
    int kc = fk % KC, ct = fk / KC;
    int n = ct * 16 + (lane & 15);
    int kb = kc * 32 + ((lane >> 4) & 3) * 8;
    int half = (n >= 96) ? 1 : 0;
    int jj = n - 96 * half;
    int e = jj >> 5, o = jj & 31;
    const float* wp = eW + ((size_t)((e * 2 + half) * IN) + kb) * 32 + o;
    bf16x8_t hv, lv;
#pragma unroll
    for (int j = 0; j < 8; ++j) {
      unsigned short h, l;
      cvt_split(wp[(size_t)j * 32], h, l);
      hv[j] = (short)h;
      lv[j] = (short)l;
    }
    *(bf16x8_t*)(wfh + (size_t)id * 4) = hv;
    *(bf16x8_t*)(wfl + (size_t)id * 4) = lv;
    return;
  }
  int id2 = id - 12 * KC * 64;
  if (id2 >= 2 * CT * 3 * 64) return;
  // nW frag: B[lane][j] = nW[t][kc*32 + ((lane>>4)&3)*8 + j][ct*16 + (lane&15)]
  int lane = id2 & 63;
  int fk = id2 >> 6;
  int kc = fk % 3;
  int ct = (fk / 3) % CT;
  int t = fk / (3 * CT);
  const float* wp = nW + ((size_t)t * 96 + kc * 32 + ((lane >> 4) & 3) * 8) * OUT +
                    ct * 16 + (lane & 15);
  bf16x8_t hv, lv;
#pragma unroll
  for (int j = 0; j < 8; ++j) {
    unsigned short h, l;
    cvt_split(wp[(size_t)j * OUT], h, l);
    hv[j] = (short)h;
    lv[j] = (short)l;
  }
  *(bf16x8_t*)(wnh + (size_t)id2 * 4) = hv;
  *(bf16x8_t*)(wnl + (size_t)id2 * 4) = lv;
}

// ---------------- node projection GEMM via MFMA (device body; fp16 P output) --------

template <int IN>
__device__ __forceinline__ void proj_dev(int bid,
                                         const float* __restrict__ X,
                                         const float* __restrict__ wfh,
                                         const float* __restrict__ wfl,
                                         f16* __restrict__ P, int n) {
  constexpr int KC = IN / 32;
  __shared__ short Ah[4 * KC * 64 * 8];
  __shared__ short Al[4 * KC * 64 * 8];
  const int tx = threadIdx.x;
  const int base = bid * 64;

  for (int q = tx; q < 4 * KC * 64; q += 256) {
    int lane = q & 63;
    int fk = q >> 6;
    int kc = fk % KC, nt = fk / KC;
    int node = base + nt * 16 + (lane & 15);
    int kb = kc * 32 + ((lane >> 4) & 3) * 8;
    float xs[8];
    if (node < n) {
      float4 a = *(const float4*)(X + (size_t)node * IN + kb);
      float4 b = *(const float4*)(X + (size_t)node * IN + kb + 4);
      xs[0] = a.x; xs[1] = a.y; xs[2] = a.z; xs[3] = a.w;
      xs[4] = b.x; xs[5] = b.y; xs[6] = b.z; xs[7] = b.w;
    } else {
#pragma unroll
      for (int j = 0; j < 8; ++j) xs[j] = 0.f;
    }
    bf16x8_t hv, lv;
#pragma unroll
    for (int j = 0; j < 8; ++j) {
      unsigned short h, l;
      cvt_split(xs[j], h, l);
      hv[j] = (short)h;
      lv[j] = (short)l;
    }
    *(bf16x8_t*)(Ah + (size_t)q * 8) = hv;
    *(bf16x8_t*)(Al + (size_t)q * 8) = lv;
  }
  __syncthreads();

  const int wave = tx >> 6;
  const int lane = tx & 63;

  f32x4_t acc[4][3];
#pragma unroll
  for (int nt = 0; nt < 4; ++nt)
#pragma unroll
    for (int c = 0; c < 3; ++c) acc[nt][c] = (f32x4_t){0.f, 0.f, 0.f, 0.f};

  for (int kc = 0; kc < KC; ++kc) {
    bf16x8_t Bh[3], Bl[3];
#pragma unroll
    for (int c = 0; c < 3; ++c) {
      int ct = wave * 3 + c;
      size_t idx = ((size_t)(ct * KC + kc) * 64 + lane) * 4;
      Bh[c] = *(const bf16x8_t*)(wfh + idx);
      Bl[c] = *(const bf16x8_t*)(wfl + idx);
    }
#pragma unroll
    for (int nt = 0; nt < 4; ++nt) {
      size_t idx = ((size_t)(nt * KC + kc) * 64 + lane) * 8;
      bf16x8_t ah = *(const bf16x8_t*)(Ah + idx);
      bf16x8_t al = *(const bf16x8_t*)(Al + idx);
#pragma unroll
      for (int c = 0; c < 3; ++c) {
        acc[nt][c] = __builtin_amdgcn_mfma_f32_16x16x32_bf16(ah, Bh[c], acc[nt][c], 0, 0, 0);
        acc[nt][c] = __builtin_amdgcn_mfma_f32_16x16x32_bf16(ah, Bl[c], acc[nt][c], 0, 0, 0);
        acc[nt][c] = __builtin_amdgcn_mfma_f32_16x16x32_bf16(al, Bh[c], acc[nt][c], 0, 0, 0);
      }
    }
  }

  const int row0 = ((lane >> 4) & 3) * 4;
  const int col = lane & 15;
#pragma unroll
  for (int nt = 0; nt < 4; ++nt) {
#pragma unroll
    for (int c = 0; c < 3; ++c) {
      int jcol = (wave * 3 + c) * 16 + col;
#pragma unroll
      for (int r = 0; r < 4; ++r) {
        int node = base + nt * 16 + row0 + r;
        if (node < n) P[(size_t)node * 192 + jcol] = (f16)acc[nt][c][r];
      }
    }
  }
}

template <int IN>
__global__ __launch_bounds__(256) void proj_mfma(const float* __restrict__ X,
                                                 const float* __restrict__ wfh,
                                                 const float* __restrict__ wfl,
                                                 f16* __restrict__ P, int n) {
  proj_dev<IN>(blockIdx.x, X, wfh, wfl, P, n);
}

// ---------------- one-pass bucket scatter (device body) ----------------
// bucket[d*64 + atomicAdd(cnt[d])] = src*384 + et*65. Capacity 64 (P(deg>=64)~4e-18).

__device__ __forceinline__ void scatter_dev(int i,
                                            const int* __restrict__ src,
                                            const int* __restrict__ dst,
                                            const int* __restrict__ etype,
                                            int* __restrict__ cnt,
                                            int* __restrict__ bucket) {
  int d = dst[i];
  int pos = atomicAdd(&cnt[d], 1);
  if (pos < 64) bucket[(size_t)d * 64 + pos] = src[i] * 384 + etype[i] * 65;
}

// ---------------- D1: prep(36) + partition + scatter edges [0, e1) ----------------

__global__ __launch_bounds__(256) void fusedA(const float* __restrict__ eW0,
                                              float* __restrict__ wf0h, float* __restrict__ wf0l,
                                              const float* __restrict__ nW1,
                                              float* __restrict__ wn1h, float* __restrict__ wn1l,
                                              const float* __restrict__ eW1,
                                              float* __restrict__ wf1h, float* __restrict__ wf1l,
                                              const float* __restrict__ nW0,
                                              float* __restrict__ wn0h, float* __restrict__ wn0l,
                                              const int* __restrict__ src,
                                              const int* __restrict__ dst,
                                              const int* __restrict__ etype,
                                              int* __restrict__ cnt,
                                              int* __restrict__ bucket, int e1,
                                              const int* __restrict__ ntype,
                                              int* __restrict__ idxbuf,
                                              int* __restrict__ tcnt, int n, int ncap,
                                              int pargrid) {
  int bid = blockIdx.x;
  if (bid < 24) {
    prep_dev<128, 128>(bid * 256 + threadIdx.x, eW0, wf0h, wf0l, nW1, wn1h, wn1l);
    return;
  }
  if (bid < 36) {
    prep_dev<64, 64>((bid - 24) * 256 + threadIdx.x, eW1, wf1h, wf1l, nW0, wn0h, wn0l);
    return;
  }
  bid -= 36;
  if (bid < pargrid) {
    int i = bid * 256 + threadIdx.x;
    int lane = threadIdx.x & 63;
    int t = (i < n) ? ntype[i] : -1;
    unsigned long long m0 = __ballot(t == 0);
    unsigned long long m1 = __ballot(t == 1);
    int b0 = 0, b1 = 0;
    if (lane == 0) {
      b0 = atomicAdd(&tcnt[0], (int)__popcll(m0));
      b1 = atomicAdd(&tcnt[1], (int)__popcll(m1));
    }
    b0 = __shfl(b0, 0);
    b1 = __shfl(b1, 0);
    unsigned long long below = (1ull << lane) - 1ull;
    if (t == 0) idxbuf[b0 + (int)__popcll(m0 & below)] = i;
    else if (t == 1) idxbuf[ncap + b1 + (int)__popcll(m1 & below)] = i;
    return;
  }
  bid -= pargrid;
  int i = bid * 256 + threadIdx.x;
  if (i < e1) scatter_dev(i, src, dst, etype, cnt, bucket);
}

// ---------------- D2: scatter edges [e1, E) + ALL proj128, stride interleave --------

__global__ __launch_bounds__(256) void fusedB(const float* __restrict__ X,
                                              const float* __restrict__ wfh,
                                              const float* __restrict__ wfl,
                                              f16* __restrict__ P, int n,
                                              int npb, int stride,
                                              const int* __restrict__ src,
                                              const int* __restrict__ dst,
                                              const int* __restrict__ etype,
                                              int* __restrict__ cnt,
                                              int* __restrict__ bucket,
                                              int e1, int E) {
  int bid = blockIdx.x;
  int pb = bid / stride;
  if ((bid % stride) == 0 && pb < npb) {
    proj_dev<128>(pb, X, wfh, wfl, P, n);
    return;
  }
  int nproj_before = (bid % stride == 0) ? pb : (pb + 1);
  if (nproj_before > npb) nproj_before = npb;
  int j = bid - nproj_before;
  int i = e1 + j * 256 + threadIdx.x;
  if (i < E) scatter_dev(i, src, dst, etype, cnt, bucket);
}

// ---------------- edge aggregation (fp16, 8-lane/edge; et in bucket low bits) -------

#define ACC_EDGEH(pk, v)                                              \
  {                                                                   \
    int et_ = (pk) & 3;                                               \
    bool e0_ = (et_ == 0), e1_ = (et_ == 1), e2_ = (et_ == 2);        \
    _Pragma("unroll")                                                 \
    for (int j = 0; j < 4; ++j) {                                     \
      float pb_ = e0_ ? pdb0[j] : (e1_ ? pdb1[j] : pdb2[j]);          \
      float m_ = fmaxf((float)(v)[j] + pb_, 0.f);                     \
      a0[j] += e0_ ? m_ : 0.f;                                        \
      a1[j] += e1_ ? m_ : 0.f;                                        \
      a2[j] += e2_ ? m_ : 0.f;                                        \
    }                                                                 \
    c0 += e0_; c1 += e1_;                                             \
  }

__global__ __launch_bounds__(256) void aggregate_kernel(const f16* __restrict__ P,
                                                        const int* __restrict__ cnt,
                                                        const int* __restrict__ bucket,
                                                        const float* __restrict__ eb,
                                                        f16* __restrict__ h, int n) {
  int wid = (blockIdx.x * 256 + threadIdx.x) >> 6;
  if (wid >= n) return;
  int lane = threadIdx.x & 63;
  int co = (lane & 7) * 4;   // 4 halves per lane within the 32-col chunk
  int cb = co * 2;           // byte offset within the 64B chunk
  int slot = lane >> 3;      // 0..7 : 8 edges per wave load round
  const f16* Pd = P + (size_t)wid * 192 + 96;
  float pdb0[4], pdb1[4], pdb2[4];
  {
    f16x4_t d0 = *(const f16x4_t*)(Pd + co);
    f16x4_t d1 = *(const f16x4_t*)(Pd + 32 + co);
    f16x4_t d2 = *(const f16x4_t*)(Pd + 64 + co);
    float4 e0 = *(const float4*)(eb + co);
    float4 e1 = *(const float4*)(eb + 32 + co);
    float4 e2 = *(const float4*)(eb + 64 + co);
    pdb0[0] = (float)d0[0] + e0.x; pdb0[1] = (float)d0[1] + e0.y;
    pdb0[2] = (float)d0[2] + e0.z; pdb0[3] = (float)d0[3] + e0.w;
    pdb1[0] = (float)d1[0] + e1.x; pdb1[1] = (float)d1[1] + e1.y;
    pdb1[2] = (float)d1[2] + e1.z; pdb1[3] = (float)d1[3] + e1.w;
    pdb2[0] = (float)d2[0] + e2.x; pdb2[1] = (float)d2[1] + e2.y;
    pdb2[2] = (float)d2[2] + e2.z; pdb2[3] = (float)d2[3] + e2.w;
  }
  int cn = cnt[wid];
  cn = (cn > 64) ? 64 : cn;
  int s = wid * 64;
  int e = s + cn;
  const char* Pb = (const char*)P;
  float a0[4], a1[4], a2[4];
#pragma unroll
  for (int j = 0; j < 4; ++j) { a0[j] = 0.f; a1[j] = 0.f; a2[j] = 0.f; }
  int c0 = 0, c1 = 0;
  for (int i = s + slot; i < e; i += 16) {
    int p0 = bucket[i];
    int p1 = 3;                     // sentinel: et bits = 3 -> accumulates nothing
    int ii = i + 8;
    if (ii < e) p1 = bucket[ii];
    f16x4_t v0 = *(const f16x4_t*)(Pb + (size_t)(p0 & ~3) + cb);
    f16x4_t v1 = *(const f16x4_t*)(Pb + (size_t)(p1 & ~3) + cb);
    ACC_EDGEH(p0, v0)
    ACC_EDGEH(p1, v1)
  }
#pragma unroll
  for (int off = 8; off < 64; off <<= 1) {
#pragma unroll
    for (int j = 0; j < 4; ++j) {
      a0[j] += __shfl_xor(a0[j], off);
      a1[j] += __shfl_xor(a1[j], off);
      a2[j] += __shfl_xor(a2[j], off);
    }
    c0 += __shfl_xor(c0, off);
    c1 += __shfl_xor(c1, off);
  }
  if (slot == 0) {
    int total = cn;
    float d0 = fmaxf((float)c0, 1.f);
    float d1 = fmaxf((float)c1, 1.f);
    float d2 = fmaxf((float)(total - c0 - c1), 1.f);
    f16* hn = h + (size_t)wid * 96;
    f16x4_t o0, o1, o2;
#pragma unroll
    for (int j = 0; j < 4; ++j) {
      o0[j] = (f16)(a0[j] / d0);
      o1[j] = (f16)(a1[j] / d1);
      o2[j] = (f16)(a2[j] / d2);
    }
    *(f16x4_t*)(hn + co)      = o0;
    *(f16x4_t*)(hn + 32 + co) = o1;
    *(f16x4_t*)(hn + 64 + co) = o2;
  }
}

// ---------------- node MLP via MFMA (type-partitioned gathered GEMM, fp16 H) --------

template <int OUT>
__global__ __launch_bounds__(256) void mlp2_mfma(const f16* __restrict__ H,
                                                 const float* __restrict__ wnh,
                                                 const float* __restrict__ wnl,
                                                 const float* __restrict__ nb,
                                                 const int* __restrict__ idxbuf,
                                                 const int* __restrict__ tcnt,
                                                 float* __restrict__ out, int ncap) {
  constexpr int CT = OUT / 16;
  constexpr int CW = CT / 4;  // col-tiles per wave
  __shared__ short Ah[12 * 64 * 8];  // [mt*3+kc][lane][8]
  __shared__ short Al[12 * 64 * 8];

  int c0 = tcnt[0];
  int nb0 = (c0 + 63) >> 6;
  int t, base, cnt;
  if ((int)blockIdx.x < nb0) {
    t = 0; base = blockIdx.x << 6; cnt = c0;
  } else {
    t = 1; base = ((int)blockIdx.x - nb0) << 6; cnt = tcnt[1];
    if (base >= cnt) return;
  }
  const int* il = idxbuf + (size_t)t * ncap;
  const float* bias = nb + t * OUT;

  const int tx = threadIdx.x;
  for (int q = tx; q < 12 * 64; q += 256) {
    int lane = q & 63;
    int fk = q >> 6;
    int kc = fk % 3, mt = fk / 3;
    int slot = base + mt * 16 + (lane & 15);
    int kb = kc * 32 + ((lane >> 4) & 3) * 8;
    float xs[8];
    if (slot < cnt) {
      int row = il[slot];
      f16x8_t a = *(const f16x8_t*)(H + (size_t)row * 96 + kb);
#pragma unroll
      for (int j = 0; j < 8; ++j) xs[j] = (float)a[j];
    } else {
#pragma unroll
      for (int j = 0; j < 8; ++j) xs[j] = 0.f;
    }
    bf16x8_t hv, lv;
#pragma unroll
    for (int j = 0; j < 8; ++j) {
      unsigned short h, l;
      cvt_split(xs[j], h, l);
      hv[j] = (short)h;
      lv[j] = (short)l;
    }
    *(bf16x8_t*)(Ah + (size_t)q * 8) = hv;
    *(bf16x8_t*)(Al + (size_t)q * 8) = lv;
  }
  __syncthreads();

  const int wave = tx >> 6;
  const int lane = tx & 63;

  f32x4_t acc[4][CW];
#pragma unroll
  for (int mt = 0; mt < 4; ++mt)
#pragma unroll
    for (int c = 0; c < CW; ++c) acc[mt][c] = (f32x4_t){0.f, 0.f, 0.f, 0.f};

  for (int kc = 0; kc < 3; ++kc) {
    bf16x8_t Bh[CW], Bl[CW];
#pragma unroll
    for (int c = 0; c < CW; ++c) {
      int ct = wave * CW + c;
      size_t idx = ((size_t)((t * CT + ct) * 3 + kc) * 64 + lane) * 4;
      Bh[c] = *(const bf16x8_t*)(wnh + idx);
      Bl[c] = *(const bf16x8_t*)(wnl + idx);
    }
#pragma unroll
    for (int mt = 0; mt < 4; ++mt) {
      size_t idx = ((size_t)((mt * 3 + kc) * 64) + lane) * 8;
      bf16x8_t ah = *(const bf16x8_t*)(Ah + idx);
      bf16x8_t al = *(const bf16x8_t*)(Al + idx);
#pragma unroll
      for (int c = 0; c < CW; ++c) {
        acc[mt][c] = __builtin_amdgcn_mfma_f32_16x16x32_bf16(ah, Bh[c], acc[mt][c], 0, 0, 0);
        acc[mt][c] = __builtin_amdgcn_mfma_f32_16x16x32_bf16(ah, Bl[c], acc[mt][c], 0, 0, 0);
        acc[mt][c] = __builtin_amdgcn_mfma_f32_16x16x32_bf16(al, Bh[c], acc[mt][c], 0, 0, 0);
      }
    }
  }

  const int row0 = ((lane >> 4) & 3) * 4;
  const int col = lane & 15;
#pragma unroll
  for (int mt = 0; mt < 4; ++mt) {
#pragma unroll
    for (int c = 0; c < CW; ++c) {
      int jcol = (wave * CW + c) * 16 + col;
      float bj = bias[jcol];
#pragma unroll
      for (int r = 0; r < 4; ++r) {
        int slot = base + mt * 16 + row0 + r;
        if (slot < cnt) {
          int row = il[slot];
          out[(size_t)row * OUT + jcol] = fmaxf(acc[mt][c][r] + bj, 0.f);
        }
      }
    }
  }
}

// ---------------- launch ----------------

extern "C" void kernel_launch(void* const* d_in, const int* in_sizes, int n_in,
                              void* d_out, int out_size, void* d_ws, size_t ws_size,
                              hipStream_t stream) {
  const float* nf    = (const float*)d_in[0];
  const int*   eidx  = (const int*)d_in[1];
  const int*   etype = (const int*)d_in[2];
  const int*   ntype = (const int*)d_in[3];
  const float* eW0   = (const float*)d_in[4];
  const float* eb0   = (const float*)d_in[5];
  const float* nW0   = (const float*)d_in[6];
  const float* nb0   = (const float*)d_in[7];
  const float* eW1   = (const float*)d_in[8];
  const float* eb1   = (const float*)d_in[9];
  const float* nW1   = (const float*)d_in[10];
  const float* nb1   = (const float*)d_in[11];
  const int N = in_sizes[3];
  const int E = in_sizes[2];
  const int* srcv = eidx;
  const int* dstv = eidx + E;

  // workspace layout. fp16 P uses the FIRST half of its fp32-sized region; the free
  // upper half [N*96, N*192) floats hosts the bucket array (N*64 ints <= N*96 floats).
  float* ws  = (float*)d_ws;
  f16*   P   = (f16*)ws;                               // N*192 f16 = N*96 floats
  int* bucket = (int*)(ws + (size_t)N * 96);           // N*64 ints (in P region's free half)
  f16*   h96 = (f16*)(ws + (size_t)N * 192);           // region N*96 floats
  float* h64 = ws + (size_t)N * 192 + (size_t)N * 96;  // region N*64 floats
  int* cnt_     = (int*)(h64 + (size_t)N * 64);   // N
  int* tcnt     = cnt_ + ((N + 4) & ~3);          // 2 (+pad)
  int* idxbuf   = tcnt + 4;                       // 2*N
  float* wf0h   = (float*)(idxbuf + 2 * N);       // 12288
  float* wf0l   = wf0h + 12288;                   // 12288
  float* wf1h   = wf0l + 12288;                   // 6144
  float* wf1l   = wf1h + 6144;                    // 6144
  float* wn0h   = wf1l + 6144;                    // 6144
  float* wn0l   = wn0h + 6144;                    // 6144
  float* wn1h   = wn0l + 6144;                    // 12288
  float* wn1l   = wn1h + 12288;                   // 12288

  const int pargrid = (N + 255) / 256;
  const int pgrid = (N + 63) / 64;
  const int e1 = (E / 2 + 255) & ~255;            // scatter split, 256-aligned
  const int sg1 = (e1 + 255) / 256;               // D1 scatter blocks
  const int sg2 = (E - e1 + 255) / 256;           // D2 scatter blocks

  // 0) zero cnt + tcnt (one contiguous fill).
  hipMemsetAsync(cnt_, 0, (size_t)(((N + 4) & ~3) + 4) * sizeof(int), stream);
  // 1) D1: prep(36) + partition + scatter[0, e1).
  fusedA<<<36 + pargrid + sg1, 256, 0, stream>>>(
      eW0, wf0h, wf0l, nW1, wn1h, wn1l,
      eW1, wf1h, wf1l, nW0, wn0h, wn0l,
      srcv, dstv, etype, cnt_, bucket, e1,
      ntype, idxbuf, tcnt, N, N, pargrid);
  // 2) D2: scatter[e1, E) + ALL proj128 (stride interleave).
  {
    int G = pgrid + sg2;
    int stride = G / pgrid;
    if (stride < 1) stride = 1;
    fusedB<<<G, 256, 0, stream>>>(nf, wf0h, wf0l, P, N, pgrid, stride,
                                  srcv, dstv, etype, cnt_, bucket, e1, E);
  }

  int agrid = (N + 3) / 4;
  int mgrid = (N + 63) / 64 + 2;

  // layer 0: aggregate -> mlp2<64> (fp32 h64) ; layer 1: proj64 -> aggregate -> mlp2<128>.
  aggregate_kernel<<<agrid, 256, 0, stream>>>(P, cnt_, bucket, eb0, h96, N);
  mlp2_mfma<64><<<mgrid, 256, 0, stream>>>(h96, wn0h, wn0l, nb0, idxbuf, tcnt, h64, N);
  proj_mfma<64><<<pgrid, 256, 0, stream>>>(h64, wf1h, wf1l, P, N);
  aggregate_kernel<<<agrid, 256, 0, stream>>>(P, cnt_, bucket, eb1, h96, N);
  mlp2_mfma<128><<<mgrid, 256, 0, stream>>>(h96, wn1h, wn1l, nb1, idxbuf, tcnt, (float*)d_out, N);
}